// Round 9
// baseline (429.680 us; speedup 1.0000x reference)
//
#include <hip/hip_runtime.h>
#include <math.h>
#include <limits.h>

#define TPB   256
#define TILE  1024          // sort: items per block-tile (256 thr x 4 rounds)
#define RNDS  4
#define MAXT  2048
#define TSTR  2056          // sparse-table row stride (u16 elements)
#define MAXK  1024
#define CSTR  32            // barrier counter stride in words (128B slots)

// ===========================================================================
// Grid barrier (round-8 proven): padded counter, RMW arrive, relaxed polling.
// ===========================================================================
__device__ inline void gbar(unsigned* ctr, int idx, unsigned nblk) {
  __syncthreads();
  if (threadIdx.x == 0) {
    unsigned* c = ctr + idx * CSTR;
    __threadfence();
    atomicAdd(c, 1u);
    while (__hip_atomic_load(c, __ATOMIC_RELAXED, __HIP_MEMORY_SCOPE_AGENT)
           < nblk)
      __builtin_amdgcn_s_sleep(2);
    __threadfence();
  }
  __syncthreads();
}

// ===========================================================================
// Kernel A: fused key-build + 4-pass LSD radix argsort (60 blocks).
// UNCHANGED from round 8 (isolate the greedy A/B).
// ===========================================================================
struct SortSM {
  union {
    unsigned h[4 * 256];
    struct {
      unsigned wcnt[4][256];
      unsigned runCnt[256];
      unsigned baseL[256];
    } pass;
  };
};

__global__ void __launch_bounds__(TPB, 1) sort_kernel(
    const float* __restrict__ scores, const float* __restrict__ mask,
    int N, int nT, unsigned* ctr, unsigned* ghist, unsigned* tileCnt,
    unsigned long long* kvA, unsigned long long* kvB, int* idxOut) {
  __shared__ SortSM s;
  const int tid = threadIdx.x;
  const int lane = tid & 63;
  const int wave = tid >> 6;

  for (int j = tid; j < 1024; j += TPB) s.h[j] = 0;
  __syncthreads();
  {
    const int tile0 = blockIdx.x * TILE;
    for (int r = 0; r < RNDS; ++r) {
      int i = tile0 + r * 256 + tid;
      if (i < N) {
        float kf = scores[i] + logf(mask[i]);          // mask==1 -> +0 exact
        unsigned u = __float_as_uint(kf);
        u = (u & 0x80000000u) ? ~u : (u | 0x80000000u);
        u = ~u;                                        // descending order
        kvA[i] = ((unsigned long long)u << 32) | (unsigned)i;
        atomicAdd(&s.h[(u & 255u)], 1u);
        atomicAdd(&s.h[256 + ((u >> 8) & 255u)], 1u);
        atomicAdd(&s.h[512 + ((u >> 16) & 255u)], 1u);
        atomicAdd(&s.h[768 + (u >> 24)], 1u);
      }
    }
    __syncthreads();
    for (int j = tid; j < 1024; j += TPB)
      if (s.h[j]) atomicAdd(&ghist[j], s.h[j]);
  }
  gbar(ctr, 0, nT);

  if (blockIdx.x == 0) {
    for (int p = 0; p < 4; ++p) {
      unsigned v = ghist[p * 256 + tid];
      unsigned* A = s.pass.wcnt[0];
      unsigned* B = s.pass.wcnt[1];
      A[tid] = v;
      __syncthreads();
      for (int off = 1; off < 256; off <<= 1) {
        B[tid] = A[tid] + ((tid >= off) ? A[tid - off] : 0u);
        __syncthreads();
        unsigned* t = A; A = B; B = t;
      }
      ghist[p * 256 + tid] = A[tid] - v;
      __syncthreads();
    }
  }
  gbar(ctr, 1, nT);

  for (int p = 0; p < 4; ++p) {
    const unsigned long long* src = (p & 1) ? kvB : kvA;
    unsigned long long*       dst = (p & 1) ? kvA : kvB;
    const int shift = 8 * p;
    const int tile0 = blockIdx.x * TILE;

    s.pass.runCnt[tid] = 0;
    unsigned long long mykv[RNDS]; unsigned mypos[RNDS]; bool myval[RNDS];
    #pragma unroll
    for (int r = 0; r < RNDS; ++r) {
      __syncthreads();
      s.pass.wcnt[0][tid] = 0; s.pass.wcnt[1][tid] = 0;
      s.pass.wcnt[2][tid] = 0; s.pass.wcnt[3][tid] = 0;
      __syncthreads();
      int i = tile0 + r * 256 + tid;
      bool v = (i < N);
      unsigned long long kv = v ? src[i] : 0ull;
      unsigned d = ((unsigned)(kv >> 32) >> shift) & 255u;
      unsigned long long mm = __ballot(v);
      #pragma unroll
      for (int b = 0; b < 8; ++b) {
        unsigned long long bb = __ballot((d >> b) & 1u);
        mm &= ((d >> b) & 1u) ? bb : ~bb;
      }
      int rank = (int)__popcll(mm & ((1ull << lane) - 1ull));
      if (v && rank == 0) s.pass.wcnt[wave][d] = (unsigned)__popcll(mm);
      __syncthreads();
      unsigned run0 = s.pass.runCnt[tid];
      unsigned run = 0;
      #pragma unroll
      for (int w2 = 0; w2 < 4; ++w2) {
        unsigned c = s.pass.wcnt[w2][tid];
        s.pass.wcnt[w2][tid] = run0 + run;
        run += c;
      }
      s.pass.runCnt[tid] = run0 + run;
      __syncthreads();
      mykv[r] = kv; myval[r] = v;
      mypos[r] = v ? (s.pass.wcnt[wave][d] + (unsigned)rank) : 0u;
    }
    __syncthreads();
    tileCnt[blockIdx.x * 256 + tid] = s.pass.runCnt[tid];
    gbar(ctr, 2 + 2 * p, nT);

    unsigned baseacc = ghist[p * 256 + tid];
    for (int t = 0; t < blockIdx.x; ++t)
      baseacc += tileCnt[t * 256 + tid];
    s.pass.baseL[tid] = baseacc;
    __syncthreads();
    #pragma unroll
    for (int r = 0; r < RNDS; ++r) {
      if (myval[r]) {
        unsigned d = ((unsigned)(mykv[r] >> 32) >> shift) & 255u;
        unsigned pos = s.pass.baseL[d] + mypos[r];
        if (p < 3) dst[pos] = mykv[r];
        else       idxOut[pos] = (int)(unsigned)mykv[r];
      }
    }
    if (p < 3) gbar(ctr, 3 + 2 * p, nT);
  }
}

// ===========================================================================
// Kernel B: batch-synchronous greedy with O(1) sparse-table RMQ crossing test.
// cross1 = max s2e over (s,e] > e ; cross2 = min e2s over [s,e) < s.
// SP[j][t] = max (s2e+1) over [t, t+2^j) (0 = none);
// SQ[j][t] = min  e2s    over [t, t+2^j) (0xFFFF = none).
// Query (1<=w<32): level j=log2(w), two overlapping windows each. Width-0
// spans never cross nor block (provable from the predicate) -> auto-accept.
// ===========================================================================
__device__ inline bool qcross(const unsigned short* SP,
                              const unsigned short* SQ,
                              int s, int e, int w) {
  if (w < 32) {
    int j = 31 - __clz(w);               // 0..4
    int off = 1 << j;
    unsigned a = SP[j * TSTR + s + 1];
    unsigned b = SP[j * TSTR + e + 1 - off];
    unsigned c = SQ[j * TSTR + s];
    unsigned d = SQ[j * TSTR + e - off];
    unsigned mx = a > b ? a : b;
    unsigned mn = c < d ? c : d;
    return (mx > (unsigned)(e + 1)) | (mn < (unsigned)s);
  }
  // generic fallback (w>=32 never occurs in this data; kept for correctness)
  bool cr = false;
  for (int a0 = s + 1; a0 <= e + 1 - 16; a0 += 16)
    cr |= SP[4 * TSTR + a0] > (unsigned)(e + 1);
  cr |= SP[4 * TSTR + (e + 1 - 16)] > (unsigned)(e + 1);
  for (int a0 = s; a0 <= e - 16; a0 += 16)
    cr |= SQ[4 * TSTR + a0] < (unsigned)s;
  cr |= SQ[4 * TSTR + (e - 16)] < (unsigned)s;
  return cr;
}

__global__ void __launch_bounds__(TPB, 1) greedy_kernel(
    const int2* __restrict__ spans2,
    const float* __restrict__ scores, const int* __restrict__ order,
    const int* __restrict__ tnum_p, const int* __restrict__ keep_p,
    float* __restrict__ out, int N) {
  __shared__ unsigned short SP[5 * TSTR];
  __shared__ unsigned short SQ[5 * TSTR];
  __shared__ unsigned long long acc[MAXK];
  __shared__ unsigned long long surv[TPB];
  __shared__ int wvs[4];
  __shared__ int gcnt;

  const int tid = threadIdx.x;
  const int lane = tid & 63;
  const int wave = tid >> 6;
  const int T  = tnum_p[0];
  const int k0 = keep_p[0];
  const int k  = (k0 < MAXK) ? k0 : MAXK;
  const unsigned long long lower = (1ull << lane) - 1ull;

  for (int t = tid; t < 5 * TSTR; t += TPB) { SP[t] = 0; SQ[t] = 0xFFFF; }
  if (tid == 0) gcnt = 0;
  __syncthreads();

  // two-deep prefetch, 256-wide
  int cc = -1, cs = 0, ce = 0, nc = -1;
  if (tid < N) cc = order[tid];
  if (TPB + tid < N) nc = order[TPB + tid];
  if (cc >= 0) { int2 sp = spans2[cc]; cs = sp.x; ce = sp.y; }

  int cnt = 0;
  for (int c0 = 0; c0 < N && cnt < k; c0 += TPB) {
    int pc = nc, ps = 0, pe = 0;
    if (pc >= 0) { int2 sp = spans2[pc]; ps = sp.x; pe = sp.y; }
    int i2 = c0 + 2 * TPB + tid;
    nc = (i2 < N) ? order[i2] : -1;

    // ---- O(1) pre-check (speculative vs monotone tables) ----
    int w = ce - cs;
    bool ok = (cc >= 0) && (w == 0 || !qcross(SP, SQ, cs, ce, w));

    // ---- order-preserving survivor compression -> LDS ----
    unsigned long long bal = __ballot(ok);
    if (lane == 0) wvs[wave] = (int)__popcll(bal);
    __syncthreads();
    int wbase = 0;
    for (int w2 = 0; w2 < wave; ++w2) wbase += wvs[w2];
    int ns = wvs[0] + wvs[1] + wvs[2] + wvs[3];
    if (ok) {
      int pos = wbase + (int)__popcll(bal & lower);
      surv[pos] = ((unsigned long long)(unsigned)cs << 48)
                | ((unsigned long long)(unsigned)ce << 32)
                | (unsigned)cc;
    }
    __syncthreads();

    // ---- wave-0 resolution: re-check (O(1)) + acceptance-broadcast ----
    if (tid < 64) {
      for (int g = 0; g < ns && cnt < k; g += 64) {
        int m = ns - g; if (m > 64) m = 64;
        bool act = lane < m;
        unsigned long long pk = act ? surv[g + lane] : 0ull;
        int gs = (int)(pk >> 48);
        int ge = (int)((pk >> 32) & 0xFFFFu);
        int gc = (int)(unsigned)pk;
        int gw = ge - gs;
        bool pre = act && (gw == 0 || !qcross(SP, SQ, gs, ge, gw));
        unsigned long long rem = __ballot(pre);
        if (rem == 0ull) continue;
        unsigned long long accm = 0ull;
        int cnt0g = cnt;
        while (rem && cnt < k) {
          int j = __ffsll((long long)rem) - 1;
          rem &= rem - 1;
          accm |= 1ull << j;
          cnt++;
          int sa = __shfl(gs, j), ea = __shfl(ge, j);
          if (ea > sa) {                 // width-0 never blocks: skip update
            // point update: all 64 lanes write distinct sparse-table entries
            if (lane < 31) {
              int jl = 31 - __clz(lane + 1);
              int off = lane + 1 - (1 << jl);
              int idx = sa - off;
              if (idx >= 0) {
                unsigned short* pp = &SP[jl * TSTR + idx];
                unsigned short v = (unsigned short)(ea + 1);
                if (*pp < v) *pp = v;
              }
            } else if (lane >= 32 && lane < 63) {
              int l2 = lane - 32;
              int jl = 31 - __clz(l2 + 1);
              int off = l2 + 1 - (1 << jl);
              int idx = ea - off;
              if (idx >= 0) {
                unsigned short* pp = &SQ[jl * TSTR + idx];
                unsigned short v = (unsigned short)sa;
                if (*pp > v) *pp = v;
              }
            }
            // bulk-reject in-group crossers of (sa, ea)
            bool mycross = (gs < sa && sa <= ge && ea > ge) ||
                           (sa < gs && gs <= ea && ea < ge);
            rem &= ~__ballot(mycross);
          }
        }
        bool accme = ((accm >> lane) & 1ull) != 0ull;
        if (accme) {                     // acceptance order == lane order
          int rnk = (int)__popcll(accm & lower);
          acc[cnt0g + rnk] =
              ((unsigned long long)(unsigned)(gs * T + ge) << 32) | (unsigned)gc;
        }
      }
      if (lane == 0) gcnt = cnt;
    }
    __syncthreads();
    cnt = gcnt;
    cc = pc; cs = ps; ce = pe;
  }

  // ---- bitonic ascending sort of acc[0..cnt) by (s*T+e, cand) ----
  int M = 2;
  while (M < cnt) M <<= 1;
  for (int j = tid; j < M; j += TPB)
    if (j >= cnt) acc[j] = ~0ull;
  __syncthreads();
  for (int kk = 2; kk <= M; kk <<= 1) {
    for (int jj = kk >> 1; jj > 0; jj >>= 1) {
      for (int i3 = tid; i3 < M; i3 += TPB) {
        int ixj = i3 ^ jj;
        if (ixj > i3) {
          unsigned long long a = acc[i3], b = acc[ixj];
          bool up = ((i3 & kk) == 0);
          if ((a > b) == up) { acc[i3] = b; acc[ixj] = a; }
        }
      }
      __syncthreads();
    }
  }

  // ---- epilogue: scores | idx | spans | valid, all f32 ----
  for (int j = tid; j < k0; j += TPB) {
    if (j < cnt) {
      int cand = (int)(acc[j] & 0xFFFFFFFFu);
      int2 sp = spans2[cand];
      out[j]                  = scores[cand];
      out[k0 + j]             = (float)cand;
      out[2 * k0 + 2 * j]     = (float)sp.x;
      out[2 * k0 + 2 * j + 1] = (float)sp.y;
      out[4 * k0 + j]         = 1.0f;
    } else {
      out[j]                  = 0.0f;
      out[k0 + j]             = 0.0f;
      out[2 * k0 + 2 * j]     = 0.0f;
      out[2 * k0 + 2 * j + 1] = 0.0f;
      out[4 * k0 + j]         = 0.0f;
    }
  }
}

extern "C" void kernel_launch(void* const* d_in, const int* in_sizes, int n_in,
                              void* d_out, int out_size, void* d_ws, size_t ws_size,
                              hipStream_t stream) {
  const int*   spans  = (const int*)d_in[0];
  const float* scores = (const float*)d_in[1];
  const float* mask   = (const float*)d_in[2];
  const int*   tnum   = (const int*)d_in[3];
  const int*   keep   = (const int*)d_in[4];
  const int N = in_sizes[1];
  const int nT = (N + TILE - 1) / TILE;   // 60 for N=61440

  // ws: kvA[N] u64 | kvB[N] u64 | ctr[16*CSTR] | ghist[1024] | tileCnt | idxOut
  char* p = (char*)d_ws;
  unsigned long long* kvA = (unsigned long long*)p;  p += (size_t)N * 8;
  unsigned long long* kvB = (unsigned long long*)p;  p += (size_t)N * 8;
  unsigned* ctr     = (unsigned*)p;                  p += 16 * CSTR * 4;
  unsigned* ghist   = (unsigned*)p;                  p += 1024 * 4;
  unsigned* tileCnt = (unsigned*)p;                  p += (size_t)nT * 256 * 4;
  int*      idxOut  = (int*)p;
  float*    out     = (float*)d_out;

  hipMemsetAsync(ctr, 0, (16 * CSTR + 1024) * sizeof(unsigned), stream);

  sort_kernel<<<nT, TPB, 0, stream>>>(scores, mask, N, nT, ctr, ghist,
                                      tileCnt, kvA, kvB, idxOut);
  greedy_kernel<<<1, TPB, 0, stream>>>((const int2*)spans, scores,
                                       idxOut, tnum, keep, out, N);
}

// Round 10
// 415.156 us; speedup vs baseline: 1.0350x; 1.0350x over previous
//
#include <hip/hip_runtime.h>
#include <math.h>
#include <limits.h>

#define TPB   256
#define TILE  1024          // sort: items per block-tile (256 thr x 4 rounds)
#define RNDS  4
#define MAXT  2048
#define TSTR  2056          // sparse-table row stride (u16 elements)
#define MAXK  1024
#define CSTR  32            // barrier counter stride in words (128B slots)

// ===========================================================================
// Grid barrier (round-8 proven): padded counter, RMW arrive, relaxed polling.
// ===========================================================================
__device__ inline void gbar(unsigned* ctr, int idx, unsigned nblk) {
  __syncthreads();
  if (threadIdx.x == 0) {
    unsigned* c = ctr + idx * CSTR;
    __threadfence();
    atomicAdd(c, 1u);
    while (__hip_atomic_load(c, __ATOMIC_RELAXED, __HIP_MEMORY_SCOPE_AGENT)
           < nblk)
      __builtin_amdgcn_s_sleep(2);
    __threadfence();
  }
  __syncthreads();
}

// ===========================================================================
// Kernel A: fused key-build + 4-pass LSD radix argsort (60 blocks).
// UNCHANGED from round 8/9 (isolate the greedy A/B).
// ===========================================================================
struct SortSM {
  union {
    unsigned h[4 * 256];
    struct {
      unsigned wcnt[4][256];
      unsigned runCnt[256];
      unsigned baseL[256];
    } pass;
  };
};

__global__ void __launch_bounds__(TPB, 1) sort_kernel(
    const float* __restrict__ scores, const float* __restrict__ mask,
    int N, int nT, unsigned* ctr, unsigned* ghist, unsigned* tileCnt,
    unsigned long long* kvA, unsigned long long* kvB, int* idxOut) {
  __shared__ SortSM s;
  const int tid = threadIdx.x;
  const int lane = tid & 63;
  const int wave = tid >> 6;

  for (int j = tid; j < 1024; j += TPB) s.h[j] = 0;
  __syncthreads();
  {
    const int tile0 = blockIdx.x * TILE;
    for (int r = 0; r < RNDS; ++r) {
      int i = tile0 + r * 256 + tid;
      if (i < N) {
        float kf = scores[i] + logf(mask[i]);          // mask==1 -> +0 exact
        unsigned u = __float_as_uint(kf);
        u = (u & 0x80000000u) ? ~u : (u | 0x80000000u);
        u = ~u;                                        // descending order
        kvA[i] = ((unsigned long long)u << 32) | (unsigned)i;
        atomicAdd(&s.h[(u & 255u)], 1u);
        atomicAdd(&s.h[256 + ((u >> 8) & 255u)], 1u);
        atomicAdd(&s.h[512 + ((u >> 16) & 255u)], 1u);
        atomicAdd(&s.h[768 + (u >> 24)], 1u);
      }
    }
    __syncthreads();
    for (int j = tid; j < 1024; j += TPB)
      if (s.h[j]) atomicAdd(&ghist[j], s.h[j]);
  }
  gbar(ctr, 0, nT);

  if (blockIdx.x == 0) {
    for (int p = 0; p < 4; ++p) {
      unsigned v = ghist[p * 256 + tid];
      unsigned* A = s.pass.wcnt[0];
      unsigned* B = s.pass.wcnt[1];
      A[tid] = v;
      __syncthreads();
      for (int off = 1; off < 256; off <<= 1) {
        B[tid] = A[tid] + ((tid >= off) ? A[tid - off] : 0u);
        __syncthreads();
        unsigned* t = A; A = B; B = t;
      }
      ghist[p * 256 + tid] = A[tid] - v;
      __syncthreads();
    }
  }
  gbar(ctr, 1, nT);

  for (int p = 0; p < 4; ++p) {
    const unsigned long long* src = (p & 1) ? kvB : kvA;
    unsigned long long*       dst = (p & 1) ? kvA : kvB;
    const int shift = 8 * p;
    const int tile0 = blockIdx.x * TILE;

    s.pass.runCnt[tid] = 0;
    unsigned long long mykv[RNDS]; unsigned mypos[RNDS]; bool myval[RNDS];
    #pragma unroll
    for (int r = 0; r < RNDS; ++r) {
      __syncthreads();
      s.pass.wcnt[0][tid] = 0; s.pass.wcnt[1][tid] = 0;
      s.pass.wcnt[2][tid] = 0; s.pass.wcnt[3][tid] = 0;
      __syncthreads();
      int i = tile0 + r * 256 + tid;
      bool v = (i < N);
      unsigned long long kv = v ? src[i] : 0ull;
      unsigned d = ((unsigned)(kv >> 32) >> shift) & 255u;
      unsigned long long mm = __ballot(v);
      #pragma unroll
      for (int b = 0; b < 8; ++b) {
        unsigned long long bb = __ballot((d >> b) & 1u);
        mm &= ((d >> b) & 1u) ? bb : ~bb;
      }
      int rank = (int)__popcll(mm & ((1ull << lane) - 1ull));
      if (v && rank == 0) s.pass.wcnt[wave][d] = (unsigned)__popcll(mm);
      __syncthreads();
      unsigned run0 = s.pass.runCnt[tid];
      unsigned run = 0;
      #pragma unroll
      for (int w2 = 0; w2 < 4; ++w2) {
        unsigned c = s.pass.wcnt[w2][tid];
        s.pass.wcnt[w2][tid] = run0 + run;
        run += c;
      }
      s.pass.runCnt[tid] = run0 + run;
      __syncthreads();
      mykv[r] = kv; myval[r] = v;
      mypos[r] = v ? (s.pass.wcnt[wave][d] + (unsigned)rank) : 0u;
    }
    __syncthreads();
    tileCnt[blockIdx.x * 256 + tid] = s.pass.runCnt[tid];
    gbar(ctr, 2 + 2 * p, nT);

    unsigned baseacc = ghist[p * 256 + tid];
    for (int t = 0; t < blockIdx.x; ++t)
      baseacc += tileCnt[t * 256 + tid];
    s.pass.baseL[tid] = baseacc;
    __syncthreads();
    #pragma unroll
    for (int r = 0; r < RNDS; ++r) {
      if (myval[r]) {
        unsigned d = ((unsigned)(mykv[r] >> 32) >> shift) & 255u;
        unsigned pos = s.pass.baseL[d] + mypos[r];
        if (p < 3) dst[pos] = mykv[r];
        else       idxOut[pos] = (int)(unsigned)mykv[r];
      }
    }
    if (p < 3) gbar(ctr, 3 + 2 * p, nT);
  }
}

// ===========================================================================
// Kernel B: batch-synchronous greedy. O(1) RMQ crossing test (r9-validated),
// r8 ballot-only serial acceptance (updates moved OUT of the loop), width-0
// bulk accept (width-0 spans provably never cross nor block anything).
// ===========================================================================
__device__ inline bool qcross(const unsigned short* SP,
                              const unsigned short* SQ,
                              int s, int e, int w) {
  if (w < 32) {
    int j = 31 - __clz(w);               // 0..4
    int off = 1 << j;
    unsigned a = SP[j * TSTR + s + 1];
    unsigned b = SP[j * TSTR + e + 1 - off];
    unsigned c = SQ[j * TSTR + s];
    unsigned d = SQ[j * TSTR + e - off];
    unsigned mx = a > b ? a : b;
    unsigned mn = c < d ? c : d;
    return (mx > (unsigned)(e + 1)) | (mn < (unsigned)s);
  }
  // generic fallback (w>=32 never occurs in this data; kept for correctness)
  bool cr = false;
  for (int a0 = s + 1; a0 <= e + 1 - 16; a0 += 16)
    cr |= SP[4 * TSTR + a0] > (unsigned)(e + 1);
  cr |= SP[4 * TSTR + (e + 1 - 16)] > (unsigned)(e + 1);
  for (int a0 = s; a0 <= e - 16; a0 += 16)
    cr |= SQ[4 * TSTR + a0] < (unsigned)s;
  cr |= SQ[4 * TSTR + (e - 16)] < (unsigned)s;
  return cr;
}

__global__ void __launch_bounds__(TPB, 1) greedy_kernel(
    const int2* __restrict__ spans2,
    const float* __restrict__ scores, const int* __restrict__ order,
    const int* __restrict__ tnum_p, const int* __restrict__ keep_p,
    float* __restrict__ out, int N) {
  __shared__ unsigned short SP[5 * TSTR];   // max (s2e+1) over [t, t+2^j)
  __shared__ unsigned short SQ[5 * TSTR];   // min  e2s    over [t, t+2^j)
  __shared__ unsigned long long acc[MAXK];
  __shared__ unsigned long long surv[TPB];
  __shared__ int wvs[4];
  __shared__ int gcnt;

  const int tid = threadIdx.x;
  const int lane = tid & 63;
  const int wave = tid >> 6;
  const int T  = tnum_p[0];
  const int k0 = keep_p[0];
  const int k  = (k0 < MAXK) ? k0 : MAXK;
  const unsigned long long lower = (1ull << lane) - 1ull;

  for (int t = tid; t < 5 * TSTR; t += TPB) { SP[t] = 0; SQ[t] = 0xFFFF; }
  if (tid == 0) gcnt = 0;
  __syncthreads();

  // two-deep prefetch, 256-wide
  int cc = -1, cs = 0, ce = 0, nc = -1;
  if (tid < N) cc = order[tid];
  if (TPB + tid < N) nc = order[TPB + tid];
  if (cc >= 0) { int2 sp = spans2[cc]; cs = sp.x; ce = sp.y; }

  int cnt = 0;
  for (int c0 = 0; c0 < N && cnt < k; c0 += TPB) {
    int pc = nc, ps = 0, pe = 0;
    if (pc >= 0) { int2 sp = spans2[pc]; ps = sp.x; pe = sp.y; }
    int i2 = c0 + 2 * TPB + tid;
    nc = (i2 < N) ? order[i2] : -1;

    // ---- O(1) pre-check (tables consistent: batch-synchronous) ----
    int w = ce - cs;
    bool ok = (cc >= 0) && (w == 0 || !qcross(SP, SQ, cs, ce, w));

    // ---- order-preserving survivor compression -> LDS ----
    unsigned long long bal = __ballot(ok);
    if (lane == 0) wvs[wave] = (int)__popcll(bal);
    __syncthreads();
    int wbase = 0;
    for (int w2 = 0; w2 < wave; ++w2) wbase += wvs[w2];
    int ns = wvs[0] + wvs[1] + wvs[2] + wvs[3];
    if (ok) {
      int pos = wbase + (int)__popcll(bal & lower);
      surv[pos] = ((unsigned long long)(unsigned)cs << 48)
                | ((unsigned long long)(unsigned)ce << 32)
                | (unsigned)cc;
    }
    __syncthreads();

    // ---- wave-0 resolution ----
    if (tid < 64) {
      bool updated = false;    // non-w0 acceptance in an earlier group?
      for (int g = 0; g < ns && cnt < k; g += 64) {
        int m = ns - g; if (m > 64) m = 64;
        bool act = lane < m;
        unsigned long long pk = act ? surv[g + lane] : 0ull;
        int gs = (int)(pk >> 48);
        int ge = (int)((pk >> 32) & 0xFFFFu);
        int gc = (int)(unsigned)pk;
        int gw = ge - gs;
        bool pre = act;
        if (updated)           // re-check only if tables changed this batch
          pre = act && (gw == 0 || !qcross(SP, SQ, gs, ge, gw));
        unsigned long long rem = __ballot(pre);
        if (rem == 0ull) continue;
        unsigned long long accm;
        int cnt0g = cnt;
        if (cnt + (int)__popcll(rem) <= k) {
          // width-0 bulk accept (never cross, never block, no table effect)
          unsigned long long w0 = __ballot(pre && gw == 0);
          accm = w0;
          cnt += (int)__popcll(w0);
          unsigned long long remS = rem & ~w0;
          while (remS) {
            int j = __ffsll((long long)remS) - 1;
            remS &= remS - 1;
            accm |= 1ull << j;
            cnt++;
            unsigned long long pj = surv[g + j];      // LDS broadcast
            int sa = (int)(pj >> 48), ea = (int)((pj >> 32) & 0xFFFFu);
            bool mycross = (gs < sa && sa <= ge && ea > ge) ||
                           (sa < gs && gs <= ea && ea < ge);
            remS &= ~__ballot(mycross);   // bulk-reject crossers of (sa,ea)
          }
        } else {
          // k-cap mode: strict serial order incl. width-0
          accm = 0ull;
          unsigned long long remS = rem;
          while (remS && cnt < k) {
            int j = __ffsll((long long)remS) - 1;
            remS &= remS - 1;
            accm |= 1ull << j;
            cnt++;
            unsigned long long pj = surv[g + j];
            int sa = (int)(pj >> 48), ea = (int)((pj >> 32) & 0xFFFFu);
            if (ea > sa) {
              bool mycross = (gs < sa && sa <= ge && ea > ge) ||
                             (sa < gs && gs <= ea && ea < ge);
              remS &= ~__ballot(mycross);
            }
          }
        }
        bool accme = ((accm >> lane) & 1ull) != 0ull;
        if (accme) {
          int rnk = (int)__popcll(accm & lower);
          acc[cnt0g + rnk] =
              ((unsigned long long)(unsigned)(gs * T + ge) << 32) | (unsigned)gc;
        }
        // ---- deferred sparse-table updates: non-w0 accepted only.
        // Iterations independent (no loop-carried dep) -> pipelined LDS.
        unsigned long long upd = accm & __ballot(act && gw > 0);
        if (upd) updated = true;
        while (upd) {
          int j = __ffsll((long long)upd) - 1;
          upd &= upd - 1;
          unsigned long long pj = surv[g + j];
          int sa = (int)(pj >> 48), ea = (int)((pj >> 32) & 0xFFFFu);
          if (lane < 31) {                 // SP windows covering sa
            int jl = 31 - __clz(lane + 1);
            int off = lane + 1 - (1 << jl);
            int idx = sa - off;
            if (idx >= 0) {
              unsigned short* pp = &SP[jl * TSTR + idx];
              unsigned short v = (unsigned short)(ea + 1);
              if (*pp < v) *pp = v;
            }
          } else if (lane >= 32 && lane < 63) {   // SQ windows covering ea
            int l2 = lane - 32;
            int jl = 31 - __clz(l2 + 1);
            int off = l2 + 1 - (1 << jl);
            int idx = ea - off;
            if (idx >= 0) {
              unsigned short* pp = &SQ[jl * TSTR + idx];
              unsigned short v = (unsigned short)sa;
              if (*pp > v) *pp = v;
            }
          }
        }
      }
      if (lane == 0) gcnt = cnt;
    }
    __syncthreads();
    cnt = gcnt;
    cc = pc; cs = ps; ce = pe;
  }

  // ---- bitonic ascending sort of acc[0..cnt) by (s*T+e, cand) ----
  int M = 2;
  while (M < cnt) M <<= 1;
  for (int j = tid; j < M; j += TPB)
    if (j >= cnt) acc[j] = ~0ull;
  __syncthreads();
  for (int kk = 2; kk <= M; kk <<= 1) {
    for (int jj = kk >> 1; jj > 0; jj >>= 1) {
      for (int i3 = tid; i3 < M; i3 += TPB) {
        int ixj = i3 ^ jj;
        if (ixj > i3) {
          unsigned long long a = acc[i3], b = acc[ixj];
          bool up = ((i3 & kk) == 0);
          if ((a > b) == up) { acc[i3] = b; acc[ixj] = a; }
        }
      }
      __syncthreads();
    }
  }

  // ---- epilogue: scores | idx | spans | valid, all f32 ----
  for (int j = tid; j < k0; j += TPB) {
    if (j < cnt) {
      int cand = (int)(acc[j] & 0xFFFFFFFFu);
      int2 sp = spans2[cand];
      out[j]                  = scores[cand];
      out[k0 + j]             = (float)cand;
      out[2 * k0 + 2 * j]     = (float)sp.x;
      out[2 * k0 + 2 * j + 1] = (float)sp.y;
      out[4 * k0 + j]         = 1.0f;
    } else {
      out[j]                  = 0.0f;
      out[k0 + j]             = 0.0f;
      out[2 * k0 + 2 * j]     = 0.0f;
      out[2 * k0 + 2 * j + 1] = 0.0f;
      out[4 * k0 + j]         = 0.0f;
    }
  }
}

extern "C" void kernel_launch(void* const* d_in, const int* in_sizes, int n_in,
                              void* d_out, int out_size, void* d_ws, size_t ws_size,
                              hipStream_t stream) {
  const int*   spans  = (const int*)d_in[0];
  const float* scores = (const float*)d_in[1];
  const float* mask   = (const float*)d_in[2];
  const int*   tnum   = (const int*)d_in[3];
  const int*   keep   = (const int*)d_in[4];
  const int N = in_sizes[1];
  const int nT = (N + TILE - 1) / TILE;   // 60 for N=61440

  // ws: kvA[N] u64 | kvB[N] u64 | ctr[16*CSTR] | ghist[1024] | tileCnt | idxOut
  char* p = (char*)d_ws;
  unsigned long long* kvA = (unsigned long long*)p;  p += (size_t)N * 8;
  unsigned long long* kvB = (unsigned long long*)p;  p += (size_t)N * 8;
  unsigned* ctr     = (unsigned*)p;                  p += 16 * CSTR * 4;
  unsigned* ghist   = (unsigned*)p;                  p += 1024 * 4;
  unsigned* tileCnt = (unsigned*)p;                  p += (size_t)nT * 256 * 4;
  int*      idxOut  = (int*)p;
  float*    out     = (float*)d_out;

  hipMemsetAsync(ctr, 0, (16 * CSTR + 1024) * sizeof(unsigned), stream);

  sort_kernel<<<nT, TPB, 0, stream>>>(scores, mask, N, nT, ctr, ghist,
                                      tileCnt, kvA, kvB, idxOut);
  greedy_kernel<<<1, TPB, 0, stream>>>((const int2*)spans, scores,
                                       idxOut, tnum, keep, out, N);
}